// Round 21
// baseline (312.855 us; speedup 1.0000x reference)
//
#include <hip/hip_runtime.h>
#include <hip/hip_fp16.h>

typedef unsigned short u16;
typedef unsigned int u32;

#define N_NODE 50000
#define N_EDGE 250000
#define NNZV   500000
#define RCAP   48
#define OVFCAP 4096

typedef __attribute__((ext_vector_type(8))) __bf16 bf16x8;
typedef __attribute__((ext_vector_type(4))) float f32x4;

#define WAITLGKM0() asm volatile("s_waitcnt lgkmcnt(0)" ::: "memory")
#define SBAR() __builtin_amdgcn_s_barrier()
#define SCHEDB() __builtin_amdgcn_sched_barrier(0)

static __device__ __forceinline__ u16 f2bf(float f) {
  union { float f; u32 u; } cv; cv.f = f;
  u32 u = cv.u;
  return (u16)((u + 0x7FFFu + ((u >> 16) & 1u)) >> 16);
}

static __device__ __forceinline__ u32 pk_bf16(float lo, float hi) {
  u32 r;
  asm("v_cvt_pk_bf16_f32 %0, %1, %2" : "=v"(r) : "v"(lo), "v"(hi));
  return r;
}

static __device__ __forceinline__ u16 f2bf_fast(float x) {
  return (u16)pk_bf16(x, x);
}

template<typename T>
static __device__ __forceinline__ T ldo(const void* base, u32 off) {
  return *(const T*)((const char*)base + off);
}
template<typename T>
static __device__ __forceinline__ void sto(void* base, u32 off, T v) {
  *(T*)((char*)base + off) = v;
}

// exact-erf gelu via A&S 7.1.26 poly (|erf err| <= 1.5e-7)
static __device__ __forceinline__ float gelu_f(float x) {
  float z = fabsf(x) * 0.70710678118654752f;
  float t = __builtin_amdgcn_rcpf(1.0f + 0.3275911f * z);
  float p = t * (0.254829592f + t * (-0.284496736f + t * (1.421413741f +
            t * (-1.453152027f + t * 1.061405429f))));
  float er = 1.0f - p * __expf(-z * z);
  er = copysignf(er, x);
  return 0.5f * x * (1.0f + er);
}

// weights [in=K][out=N] f32 -> per-wave register-fragment stream (16x16x32)
static __device__ __forceinline__ void wconv(const float* __restrict__ in,
                                             u16* __restrict__ out,
                                             int K, int N, int cpw, int idx) {
  int k = idx / N, n = idx % N;
  int w = n / cpw, rem = n % cpw;
  int t = rem >> 4, l15 = rem & 15;
  int ks = k >> 5, gq = (k >> 3) & 3, e = k & 7;
  int steps = K >> 5, tiles = cpw >> 4;
  size_t o = ((((size_t)(w * steps + ks) * tiles + t) * 64) + gq * 16 + l15) * 8 + e;
  out[o] = f2bf(in[(size_t)k * N + n]);
}

// merged prep: 4 weight re-layouts + row-bucket-counter zero
__global__ __launch_bounds__(256) void prep_kernel(
    const float* __restrict__ ew1, const float* __restrict__ ew2,
    const float* __restrict__ nw1, const float* __restrict__ nw2,
    u16* __restrict__ ew1r, u16* __restrict__ ew2r,
    u16* __restrict__ nw1r, u16* __restrict__ nw2r,
    u32* __restrict__ rcnt0) {
  const int S1 = 384 * 384, S2 = 384 * 128, S3 = 256 * 256, S4 = 256 * 128;
  const int SC = N_NODE + 1;   // rcnt + overflow counter
  const long total = (long)S1 + S2 + S3 + S4 + SC;
  for (long i = (long)blockIdx.x * 256 + threadIdx.x; i < total;
       i += (long)gridDim.x * 256) {
    long idx = i;
    if (idx < S1) { wconv(ew1, ew1r, 384, 384, 48, (int)idx); continue; }
    idx -= S1;
    if (idx < S2) { wconv(ew2, ew2r, 384, 128, 16, (int)idx); continue; }
    idx -= S2;
    if (idx < S3) { wconv(nw1, nw1r, 256, 256, 32, (int)idx); continue; }
    idx -= S3;
    if (idx < S4) { wconv(nw2, nw2r, 256, 128, 16, (int)idx); continue; }
    idx -= S4;
    rcnt0[idx] = 0;
  }
}

// invert COO by ROW: buck[r*RCAP+p] = (col, val_bits); overflow -> ovf list
__global__ __launch_bounds__(256) void fill_row_kernel(
    const int* __restrict__ rows, const int* __restrict__ cols,
    const float* __restrict__ vals,
    u32* __restrict__ rcnt, int2* __restrict__ buck, int4* __restrict__ ovf) {
  int k = blockIdx.x * 256 + threadIdx.x;
  if (k >= NNZV) return;
  int r = rows[k];
  u32 p = atomicAdd(&rcnt[r], 1u);
  if (p < RCAP) {
    buck[(size_t)r * RCAP + p] = make_int2(cols[k], __float_as_int(vals[k]));
  } else {
    u32 q = atomicAdd(&rcnt[N_NODE], 1u);
    if (q < OVFCAP) ovf[q] = make_int4(r, cols[k], __float_as_int(vals[k]), 0);
  }
}

// ==================== fused edge MLP (r17-proven) ============================
// 64 rows/block, 512 thr. B reg-streamed ring-3; full x (48KB) in LDS;
// h in place; edge residual in 32KB LDS. LDS 80KB -> 2 blocks/CU.
__global__ __launch_bounds__(512, 4) void edge_fused_kernel(
    const float* __restrict__ node, const float* __restrict__ edge,
    const int* __restrict__ edgeIdx,
    const float* __restrict__ lng, const float* __restrict__ lnb,
    const u16* __restrict__ w1r, const float* __restrict__ b1,
    const u16* __restrict__ w2r, const float* __restrict__ b2,
    __half* __restrict__ e_h, float* __restrict__ out_edge) {
  const int lane = threadIdx.x & 63, wid = threadIdx.x >> 6;   // 0..7
  const int l15 = lane & 15, gq = lane >> 4;
  const int row0 = blockIdx.x * 64;

  __shared__ __align__(16) u16 xp[64 * 384];      // 48 KB: x, then h (in place)
  __shared__ __align__(16) float er[64 * 128];    // 32 KB: edge residual cache

  const bf16x8* w1v = (const bf16x8*)w1r + (size_t)wid * (12 * 192) + lane;
  bf16x8 br[3][3];
#define LDB1(s, b) { br[b][0] = w1v[(s) * 192]; br[b][1] = w1v[(s) * 192 + 64]; \
                     br[b][2] = w1v[(s) * 192 + 128]; }
  LDB1(0, 0); LDB1(1, 1); LDB1(2, 2);

  float ga[6], be[6];
#pragma unroll
  for (int s = 0; s < 3; ++s) {
    float2 g2 = *(const float2*)&lng[s * 128 + 2 * lane];
    float2 b2v = *(const float2*)&lnb[s * 128 + 2 * lane];
    ga[2 * s] = g2.x; ga[2 * s + 1] = g2.y;
    be[2 * s] = b2v.x; be[2 * s + 1] = b2v.y;
  }
  {
    u32 oe[8], oa[8], ob[8];
#pragma unroll
    for (int t = 0; t < 8; ++t) {
      int g = row0 + wid * 8 + t; if (g > N_EDGE - 1) g = N_EDGE - 1;
      int2 ab = ldo<int2>(edgeIdx, (u32)g * 8);
      oe[t] = (u32)g * 512 + lane * 8;
      oa[t] = (u32)ab.x * 512 + lane * 8;
      ob[t] = (u32)ab.y * 512 + lane * 8;
    }
    float2 v0[8], v1[8], v2[8];
#pragma unroll
    for (int t = 0; t < 8; ++t) {
      v0[t] = ldo<float2>(edge, oe[t]);
      v1[t] = ldo<float2>(node, oa[t]);
      v2[t] = ldo<float2>(node, ob[t]);
    }
#pragma unroll
    for (int t = 0; t < 8; ++t) {
      int lr = wid * 8 + t;
      *(float2*)&er[lr * 128 + 2 * lane] = v0[t];
      float s  = v0[t].x + v0[t].y + v1[t].x + v1[t].y + v2[t].x + v2[t].y;
      float ss = v0[t].x*v0[t].x + v0[t].y*v0[t].y + v1[t].x*v1[t].x +
                 v1[t].y*v1[t].y + v2[t].x*v2[t].x + v2[t].y*v2[t].y;
#pragma unroll
      for (int m = 1; m < 64; m <<= 1) { s += __shfl_xor(s, m); ss += __shfl_xor(ss, m); }
      float mean = s * (1.0f / 384.0f);
      float var  = ss * (1.0f / 384.0f) - mean * mean;
      float rstd = rsqrtf(var + 1e-5f);
      float2 vv[3] = {v0[t], v1[t], v2[t]};
#pragma unroll
      for (int sg = 0; sg < 3; ++sg) {
        float y0 = (vv[sg].x - mean) * rstd * ga[2 * sg]     + be[2 * sg];
        float y1 = (vv[sg].y - mean) * rstd * ga[2 * sg + 1] + be[2 * sg + 1];
        int sl = (sg * 16 + (lane >> 2)) ^ (lr & 15);
        *(u32*)&xp[lr * 384 + sl * 8 + (lane & 3) * 2] = pk_bf16(y0, y1);
      }
    }
  }
  WAITLGKM0(); SCHEDB(); SBAR(); SCHEDB();

  f32x4 acc1[4][3];
#pragma unroll
  for (int nt = 0; nt < 3; ++nt) {
    float bv = b1[wid * 48 + nt * 16 + l15];
#pragma unroll
    for (int m = 0; m < 4; ++m) acc1[m][nt] = (f32x4){bv, bv, bv, bv};
  }
  int aoff[4];
#pragma unroll
  for (int m = 0; m < 4; ++m) aoff[m] = (m * 16 + l15) * 384;

#pragma unroll
  for (int s = 0; s < 12; ++s) {
    const int axi = ((s * 4 + gq) ^ l15) * 8;
    bf16x8 a[4];
#pragma unroll
    for (int m = 0; m < 4; ++m) a[m] = *(const bf16x8*)&xp[aoff[m] + axi];
    __builtin_amdgcn_s_setprio(1);
#pragma unroll
    for (int m = 0; m < 4; ++m)
#pragma unroll
      for (int nt = 0; nt < 3; ++nt)
        acc1[m][nt] = __builtin_amdgcn_mfma_f32_16x16x32_bf16(a[m], br[s % 3][nt], acc1[m][nt], 0, 0, 0);
    __builtin_amdgcn_s_setprio(0);
    if (s + 3 < 12) { LDB1(s + 3, s % 3); }
  }
  SCHEDB(); SBAR(); SCHEDB();

  const bf16x8* w2v = (const bf16x8*)w2r + (size_t)wid * (12 * 64) + lane;
  bf16x8 br2[3];
#define LDB2(s, b) { br2[b] = w2v[(s) * 64]; }
  LDB2(0, 0); LDB2(1, 1); LDB2(2, 2);
#pragma unroll
  for (int m = 0; m < 4; ++m)
#pragma unroll
    for (int nt = 0; nt < 3; ++nt) {
      const int c = wid * 48 + nt * 16 + l15;
#pragma unroll
      for (int j = 0; j < 4; ++j) {
        int r = m * 16 + gq * 4 + j;
        xp[r * 384 + (((c >> 3) ^ (r & 15)) * 8) + (c & 7)] = f2bf_fast(gelu_f(acc1[m][nt][j]));
      }
    }
  WAITLGKM0(); SCHEDB(); SBAR(); SCHEDB();

  float b2v = b2[wid * 16 + l15];
  f32x4 acc2[4];
#pragma unroll
  for (int m = 0; m < 4; ++m) acc2[m] = (f32x4){b2v, b2v, b2v, b2v};

#pragma unroll
  for (int g = 0; g < 12; ++g) {
    const int axi = ((g * 4 + gq) ^ l15) * 8;
    bf16x8 a[4];
#pragma unroll
    for (int m = 0; m < 4; ++m) a[m] = *(const bf16x8*)&xp[aoff[m] + axi];
    __builtin_amdgcn_s_setprio(1);
#pragma unroll
    for (int m = 0; m < 4; ++m)
      acc2[m] = __builtin_amdgcn_mfma_f32_16x16x32_bf16(a[m], br2[g % 3], acc2[m], 0, 0, 0);
    __builtin_amdgcn_s_setprio(0);
    if (g + 3 < 12) { LDB2(g + 3, g % 3); }
  }

  const int col = wid * 16 + l15;
#pragma unroll
  for (int m = 0; m < 4; ++m)
#pragma unroll
    for (int j = 0; j < 4; ++j) {
      int lr = m * 16 + gq * 4 + j;
      int r = row0 + lr;
      if (r < N_EDGE) {
        __half hv = __float2half(acc2[m][j]);
        sto<__half>(e_h, (u32)r * 256 + col * 2, hv);
        sto<float>(out_edge, (u32)r * 512 + col * 4, er[lr * 128 + col] + __half2float(hv));
      }
    }
#undef LDB1
#undef LDB2
}

// ==================== fused node MLP + inline gather =========================
// LN phase gathers agg[r] = fp16(sum e_h[col]*val) directly from row buckets
// (unroll-4, wave-uniform bucket loads); no agg tensor, no gather kernel.
// Overflow entries (normally zero) applied via compile-time-indexed adds.
__global__ __launch_bounds__(512, 4) void node_fused_kernel(
    const float* __restrict__ node, const __half* __restrict__ e_h,
    const u32* __restrict__ rcnt, const int2* __restrict__ buck,
    const int4* __restrict__ ovf,
    const float* __restrict__ lng, const float* __restrict__ lnb,
    const u16* __restrict__ w1r, const float* __restrict__ b1,
    const u16* __restrict__ w2r, const float* __restrict__ b2,
    float* __restrict__ out_node) {
  const int lane = threadIdx.x & 63, wid = threadIdx.x >> 6;
  const int l15 = lane & 15, gq = lane >> 4;
  const int row0 = blockIdx.x * 64;

  __shared__ __align__(16) u16 xp[64 * 256];      // 32 KB: x, then h
  __shared__ __align__(16) float nr[64 * 128];    // 32 KB: node residual cache

  const bf16x8* w1v = (const bf16x8*)w1r + (size_t)wid * (8 * 128) + lane;
  bf16x8 br[3][2];
#define NLDB1(s, b) { br[b][0] = w1v[(s) * 128]; br[b][1] = w1v[(s) * 128 + 64]; }
  NLDB1(0, 0); NLDB1(1, 1); NLDB1(2, 2);

  float ga[4], be[4];
#pragma unroll
  for (int s = 0; s < 2; ++s) {
    float2 g2 = *(const float2*)&lng[s * 128 + 2 * lane];
    float2 b2v = *(const float2*)&lnb[s * 128 + 2 * lane];
    ga[2 * s] = g2.x; ga[2 * s + 1] = g2.y;
    be[2 * s] = b2v.x; be[2 * s + 1] = b2v.y;
  }
  {
    float2 v0[8], v1[8];
#pragma unroll
    for (int t = 0; t < 8; ++t) {
      int g = row0 + wid * 8 + t; if (g > N_NODE - 1) g = N_NODE - 1;
      v0[t] = ldo<float2>(node, (u32)g * 512 + lane * 8);
    }
    // inline gather (f32 accumulate, rounded through fp16 to match ref agg)
#pragma unroll 2
    for (int t = 0; t < 8; ++t) {
      int g = row0 + wid * 8 + t; if (g > N_NODE - 1) g = N_NODE - 1;
      u32 n = rcnt[g]; if (n > RCAP) n = RCAP;
      const int2* bp = buck + (size_t)g * RCAP;
      float a0 = 0.0f, a1 = 0.0f;
      for (u32 p = 0; p < n; p += 4) {
        int2 e0 = bp[p];
        int2 e1 = bp[p + 1];
        int2 e2 = bp[p + 2];
        int2 e3 = bp[p + 3];
        if (p + 1 >= n) e1 = make_int2(e0.x, 0);
        if (p + 2 >= n) e2 = make_int2(e0.x, 0);
        if (p + 3 >= n) e3 = make_int2(e0.x, 0);
        __half2 h0 = ldo<__half2>(e_h, (u32)e0.x * 256 + lane * 4);
        __half2 h1 = ldo<__half2>(e_h, (u32)e1.x * 256 + lane * 4);
        __half2 h2 = ldo<__half2>(e_h, (u32)e2.x * 256 + lane * 4);
        __half2 h3 = ldo<__half2>(e_h, (u32)e3.x * 256 + lane * 4);
        float2 f0 = __half22float2(h0), f1 = __half22float2(h1);
        float2 f2 = __half22float2(h2), f3 = __half22float2(h3);
        float w0 = __int_as_float(e0.y), w1_ = __int_as_float(e1.y);
        float w2_ = __int_as_float(e2.y), w3 = __int_as_float(e3.y);
        a0 = fmaf(f0.x, w0, a0); a1 = fmaf(f0.y, w0, a1);
        a0 = fmaf(f1.x, w1_, a0); a1 = fmaf(f1.y, w1_, a1);
        a0 = fmaf(f2.x, w2_, a0); a1 = fmaf(f2.y, w2_, a1);
        a0 = fmaf(f3.x, w3, a0); a1 = fmaf(f3.y, w3, a1);
      }
      v1[t] = make_float2(a0, a1);
    }
    // overflow entries (normally none): compile-time-indexed adds (no scratch)
    {
      u32 novf = rcnt[N_NODE];
      if (novf) {
        if (novf > OVFCAP) novf = OVFCAP;
        for (u32 q = 0; q < novf; ++q) {
          int4 e = ovf[q];
          int t = e.x - (row0 + wid * 8);
          if (t >= 0 && t < 8) {
            __half2 hv = ldo<__half2>(e_h, (u32)e.y * 256 + lane * 4);
            float v = __int_as_float(e.z);
            float2 f = __half22float2(hv);
#pragma unroll
            for (int tt = 0; tt < 8; ++tt)
              if (tt == t) { v1[tt].x += f.x * v; v1[tt].y += f.y * v; }
          }
        }
      }
    }
#pragma unroll
    for (int t = 0; t < 8; ++t) {
      // round gathered sum through fp16 (ref's agg dtype), then LN
      v1[t] = __half22float2(__floats2half2_rn(v1[t].x, v1[t].y));
      int lr = wid * 8 + t;
      *(float2*)&nr[lr * 128 + 2 * lane] = v0[t];
      float s  = v0[t].x + v0[t].y + v1[t].x + v1[t].y;
      float ss = v0[t].x*v0[t].x + v0[t].y*v0[t].y + v1[t].x*v1[t].x + v1[t].y*v1[t].y;
#pragma unroll
      for (int m = 1; m < 64; m <<= 1) { s += __shfl_xor(s, m); ss += __shfl_xor(ss, m); }
      float mean = s * (1.0f / 256.0f);
      float var  = ss * (1.0f / 256.0f) - mean * mean;
      float rstd = rsqrtf(var + 1e-5f);
      float2 vv[2] = {v0[t], v1[t]};
#pragma unroll
      for (int sg = 0; sg < 2; ++sg) {
        float y0 = (vv[sg].x - mean) * rstd * ga[2 * sg]     + be[2 * sg];
        float y1 = (vv[sg].y - mean) * rstd * ga[2 * sg + 1] + be[2 * sg + 1];
        int sl = (sg * 16 + (lane >> 2)) ^ (lr & 15);
        *(u32*)&xp[lr * 256 + sl * 8 + (lane & 3) * 2] = pk_bf16(y0, y1);
      }
    }
  }
  WAITLGKM0(); SCHEDB(); SBAR(); SCHEDB();

  f32x4 acc1[4][2];
#pragma unroll
  for (int nt = 0; nt < 2; ++nt) {
    float bv = b1[wid * 32 + nt * 16 + l15];
#pragma unroll
    for (int m = 0; m < 4; ++m) acc1[m][nt] = (f32x4){bv, bv, bv, bv};
  }
  int aoff[4];
#pragma unroll
  for (int m = 0; m < 4; ++m) aoff[m] = (m * 16 + l15) * 256;

#pragma unroll
  for (int s = 0; s < 8; ++s) {
    const int axi = ((s * 4 + gq) ^ l15) * 8;
    bf16x8 a[4];
#pragma unroll
    for (int m = 0; m < 4; ++m) a[m] = *(const bf16x8*)&xp[aoff[m] + axi];
    __builtin_amdgcn_s_setprio(1);
#pragma unroll
    for (int m = 0; m < 4; ++m)
#pragma unroll
      for (int nt = 0; nt < 2; ++nt)
        acc1[m][nt] = __builtin_amdgcn_mfma_f32_16x16x32_bf16(a[m], br[s % 3][nt], acc1[m][nt], 0, 0, 0);
    __builtin_amdgcn_s_setprio(0);
    if (s + 3 < 8) { NLDB1(s + 3, s % 3); }
  }
  SCHEDB(); SBAR(); SCHEDB();

  const bf16x8* w2v = (const bf16x8*)w2r + (size_t)wid * (8 * 64) + lane;
  bf16x8 br2[3];
#define NLDB2(s, b) { br2[b] = w2v[(s) * 64]; }
  NLDB2(0, 0); NLDB2(1, 1); NLDB2(2, 2);
#pragma unroll
  for (int m = 0; m < 4; ++m)
#pragma unroll
    for (int nt = 0; nt < 2; ++nt) {
      const int c = wid * 32 + nt * 16 + l15;
#pragma unroll
      for (int j = 0; j < 4; ++j) {
        int r = m * 16 + gq * 4 + j;
        xp[r * 256 + (((c >> 3) ^ (r & 15)) * 8) + (c & 7)] = f2bf_fast(gelu_f(acc1[m][nt][j]));
      }
    }
  WAITLGKM0(); SCHEDB(); SBAR(); SCHEDB();

  float b2v = b2[wid * 16 + l15];
  f32x4 acc2[4];
#pragma unroll
  for (int m = 0; m < 4; ++m) acc2[m] = (f32x4){b2v, b2v, b2v, b2v};

#pragma unroll
  for (int g = 0; g < 8; ++g) {
    const int axi = ((g * 4 + gq) ^ l15) * 8;
    bf16x8 a[4];
#pragma unroll
    for (int m = 0; m < 4; ++m) a[m] = *(const bf16x8*)&xp[aoff[m] + axi];
    __builtin_amdgcn_s_setprio(1);
#pragma unroll
    for (int m = 0; m < 4; ++m)
      acc2[m] = __builtin_amdgcn_mfma_f32_16x16x32_bf16(a[m], br2[g % 3], acc2[m], 0, 0, 0);
    __builtin_amdgcn_s_setprio(0);
    if (g + 3 < 8) { NLDB2(g + 3, g % 3); }
  }

  const int col = wid * 16 + l15;
#pragma unroll
  for (int m = 0; m < 4; ++m)
#pragma unroll
    for (int j = 0; j < 4; ++j) {
      int lr = m * 16 + gq * 4 + j;
      int r = row0 + lr;
      if (r < N_NODE) {
        sto<float>(out_node, (u32)r * 512 + col * 4, nr[lr * 128 + col] + acc2[m][j]);
      }
    }
#undef NLDB1
#undef NLDB2
}

extern "C" void kernel_launch(void* const* d_in, const int* in_sizes, int n_in,
                              void* d_out, int out_size, void* d_ws, size_t ws_size,
                              hipStream_t stream) {
  (void)in_sizes; (void)n_in; (void)out_size; (void)ws_size;
  const float* node    = (const float*)d_in[0];
  const float* edge    = (const float*)d_in[1];
  const int*   edgeIdx = (const int*)d_in[2];
  const int*   e2n_r   = (const int*)d_in[3];
  const int*   e2n_c   = (const int*)d_in[4];
  const float* e2n_v   = (const float*)d_in[5];
  const float* n1g     = (const float*)d_in[6];
  const float* n1b     = (const float*)d_in[7];
  const float* n2g     = (const float*)d_in[8];
  const float* n2b     = (const float*)d_in[9];
  const float* ew1     = (const float*)d_in[10];
  const float* eb1     = (const float*)d_in[11];
  const float* ew2     = (const float*)d_in[12];
  const float* eb2     = (const float*)d_in[13];
  const float* nw1     = (const float*)d_in[14];
  const float* nb1     = (const float*)d_in[15];
  const float* nw2     = (const float*)d_in[16];
  const float* nb2     = (const float*)d_in[17];

  float* out_node = (float*)d_out;
  float* out_edge = out_node + (size_t)N_NODE * 128;

  char* w = (char*)d_ws;
  auto alloc = [&](size_t bytes) { char* p = w; w += (bytes + 255) & ~(size_t)255; return p; };
  u16* ew1r = (u16*)alloc((size_t)384 * 384 * 2);
  u16* ew2r = (u16*)alloc((size_t)384 * 128 * 2);
  u16* nw1r = (u16*)alloc((size_t)256 * 256 * 2);
  u16* nw2r = (u16*)alloc((size_t)256 * 128 * 2);
  __half* e_h = (__half*)alloc((size_t)N_EDGE * 128 * 2);
  u32* rcnt = (u32*)alloc((size_t)(N_NODE + 1) * 4);
  int4* ovf = (int4*)alloc((size_t)OVFCAP * 16);
  int2* buck = (int2*)alloc(((size_t)N_NODE * RCAP + 64) * 8);  // +slack for unroll-4 reads

  prep_kernel<<<1024, 256, 0, stream>>>(ew1, ew2, nw1, nw2,
                                        ew1r, ew2r, nw1r, nw2r, rcnt);

  fill_row_kernel<<<(NNZV + 255) / 256, 256, 0, stream>>>(
      e2n_r, e2n_c, e2n_v, rcnt, buck, ovf);

  edge_fused_kernel<<<(N_EDGE + 63) / 64, 512, 0, stream>>>(
      node, edge, edgeIdx, n1g, n1b, ew1r, eb1, ew2r, eb2, e_h, out_edge);

  node_fused_kernel<<<(N_NODE + 63) / 64, 512, 0, stream>>>(
      node, e_h, rcnt, buck, ovf, n2g, n2b, nw1r, nb1, nw2r, nb2, out_node);
}

// Round 22
// 282.686 us; speedup vs baseline: 1.1067x; 1.1067x over previous
//
#include <hip/hip_runtime.h>
#include <hip/hip_fp16.h>

typedef unsigned short u16;
typedef unsigned int u32;

#define N_NODE 50000
#define N_EDGE 250000
#define NNZV   500000
#define RCAP   48
#define OVFCAP 4096

typedef __attribute__((ext_vector_type(8))) __bf16 bf16x8;
typedef __attribute__((ext_vector_type(4))) float f32x4;

#define WAITLGKM0() asm volatile("s_waitcnt lgkmcnt(0)" ::: "memory")
#define SBAR() __builtin_amdgcn_s_barrier()
#define SCHEDB() __builtin_amdgcn_sched_barrier(0)

static __device__ __forceinline__ u16 f2bf(float f) {
  union { float f; u32 u; } cv; cv.f = f;
  u32 u = cv.u;
  return (u16)((u + 0x7FFFu + ((u >> 16) & 1u)) >> 16);
}

static __device__ __forceinline__ u32 pk_bf16(float lo, float hi) {
  u32 r;
  asm("v_cvt_pk_bf16_f32 %0, %1, %2" : "=v"(r) : "v"(lo), "v"(hi));
  return r;
}

static __device__ __forceinline__ u16 f2bf_fast(float x) {
  return (u16)pk_bf16(x, x);
}

template<typename T>
static __device__ __forceinline__ T ldo(const void* base, u32 off) {
  return *(const T*)((const char*)base + off);
}
template<typename T>
static __device__ __forceinline__ void sto(void* base, u32 off, T v) {
  *(T*)((char*)base + off) = v;
}

// exact-erf gelu via A&S 7.1.26 poly (|erf err| <= 1.5e-7)
static __device__ __forceinline__ float gelu_f(float x) {
  float z = fabsf(x) * 0.70710678118654752f;
  float t = __builtin_amdgcn_rcpf(1.0f + 0.3275911f * z);
  float p = t * (0.254829592f + t * (-0.284496736f + t * (1.421413741f +
            t * (-1.453152027f + t * 1.061405429f))));
  float er = 1.0f - p * __expf(-z * z);
  er = copysignf(er, x);
  return 0.5f * x * (1.0f + er);
}

// weights [in=K][out=N] f32 -> per-wave register-fragment stream (16x16x32)
static __device__ __forceinline__ void wconv(const float* __restrict__ in,
                                             u16* __restrict__ out,
                                             int K, int N, int cpw, int idx) {
  int k = idx / N, n = idx % N;
  int w = n / cpw, rem = n % cpw;
  int t = rem >> 4, l15 = rem & 15;
  int ks = k >> 5, gq = (k >> 3) & 3, e = k & 7;
  int steps = K >> 5, tiles = cpw >> 4;
  size_t o = ((((size_t)(w * steps + ks) * tiles + t) * 64) + gq * 16 + l15) * 8 + e;
  out[o] = f2bf(in[(size_t)k * N + n]);
}

// merged prep: 4 weight re-layouts + row-bucket-counter zero
__global__ __launch_bounds__(256) void prep_kernel(
    const float* __restrict__ ew1, const float* __restrict__ ew2,
    const float* __restrict__ nw1, const float* __restrict__ nw2,
    u16* __restrict__ ew1r, u16* __restrict__ ew2r,
    u16* __restrict__ nw1r, u16* __restrict__ nw2r,
    u32* __restrict__ rcnt0) {
  const int S1 = 384 * 384, S2 = 384 * 128, S3 = 256 * 256, S4 = 256 * 128;
  const int SC = N_NODE + 1;   // rcnt + overflow counter
  const long total = (long)S1 + S2 + S3 + S4 + SC;
  for (long i = (long)blockIdx.x * 256 + threadIdx.x; i < total;
       i += (long)gridDim.x * 256) {
    long idx = i;
    if (idx < S1) { wconv(ew1, ew1r, 384, 384, 48, (int)idx); continue; }
    idx -= S1;
    if (idx < S2) { wconv(ew2, ew2r, 384, 128, 16, (int)idx); continue; }
    idx -= S2;
    if (idx < S3) { wconv(nw1, nw1r, 256, 256, 32, (int)idx); continue; }
    idx -= S3;
    if (idx < S4) { wconv(nw2, nw2r, 256, 128, 16, (int)idx); continue; }
    idx -= S4;
    rcnt0[idx] = 0;
  }
}

// gather-based aggregation: agg[r] = fp16(sum_p float(e_h[col_p]) * val_p)
// 1 wave/row, unroll-4 with predicated entries (4 e_h loads in flight).
// buck has 64 entries of tail slack so speculative reads stay in-bounds.
__global__ __launch_bounds__(256) void agg_gather_kernel(
    const u32* __restrict__ rcnt, const int2* __restrict__ buck,
    const __half* __restrict__ e_h, __half* __restrict__ agg) {
  int r = __builtin_amdgcn_readfirstlane(blockIdx.x * 4 + (threadIdx.x >> 6));
  if (r >= N_NODE) return;
  int l = threadIdx.x & 63;
  u32 n = rcnt[r]; if (n > RCAP) n = RCAP;
  const int2* bp = buck + (size_t)r * RCAP;
  float a0 = 0.0f, a1 = 0.0f;
  for (u32 p = 0; p < n; p += 4) {
    int2 e0 = bp[p];
    int2 e1 = bp[p + 1];
    int2 e2 = bp[p + 2];
    int2 e3 = bp[p + 3];
    if (p + 1 >= n) e1 = make_int2(e0.x, 0);
    if (p + 2 >= n) e2 = make_int2(e0.x, 0);
    if (p + 3 >= n) e3 = make_int2(e0.x, 0);
    __half2 h0 = ldo<__half2>(e_h, (u32)e0.x * 256 + l * 4);
    __half2 h1 = ldo<__half2>(e_h, (u32)e1.x * 256 + l * 4);
    __half2 h2 = ldo<__half2>(e_h, (u32)e2.x * 256 + l * 4);
    __half2 h3 = ldo<__half2>(e_h, (u32)e3.x * 256 + l * 4);
    float2 f0 = __half22float2(h0), f1 = __half22float2(h1);
    float2 f2 = __half22float2(h2), f3 = __half22float2(h3);
    float v0 = __int_as_float(e0.y), v1 = __int_as_float(e1.y);
    float v2 = __int_as_float(e2.y), v3 = __int_as_float(e3.y);
    a0 = fmaf(f0.x, v0, a0); a1 = fmaf(f0.y, v0, a1);
    a0 = fmaf(f1.x, v1, a0); a1 = fmaf(f1.y, v1, a1);
    a0 = fmaf(f2.x, v2, a0); a1 = fmaf(f2.y, v2, a1);
    a0 = fmaf(f3.x, v3, a0); a1 = fmaf(f3.y, v3, a1);
  }
  *(__half2*)&agg[(size_t)r * 128 + 2 * l] = __floats2half2_rn(a0, a1);
}

// overflow cleanup (normally empty): atomic add e_h[c]*v into agg[r]
__global__ __launch_bounds__(256) void ovf_scatter_kernel(
    const int4* __restrict__ ovf, const u32* __restrict__ rcnt,
    const __half* __restrict__ e_h, __half* __restrict__ agg) {
  int n = (int)rcnt[N_NODE]; if (n > OVFCAP) n = OVFCAP;
  int wv = blockIdx.x * 4 + (threadIdx.x >> 6);
  int l = threadIdx.x & 63;
  for (int q = wv; q < n; q += gridDim.x * 4) {
    int4 e = ovf[q];
    __half2 hv = *(const __half2*)&e_h[(size_t)e.y * 128 + 2 * l];
    __half2 h2 = __hmul2(hv, __float2half2_rn(__int_as_float(e.z)));
    unsafeAtomicAdd((__half2*)&agg[(size_t)e.x * 128 + 2 * l], h2);
  }
}

// ==================== fused edge MLP + COO fill ==============================
// 64 rows/block, 512 thr. B reg-streamed ring-3; full x (48KB) in LDS;
// h in place; edge residual in 32KB LDS. LDS 80KB -> 2 blocks/CU.
// Prologue: one guarded bucket-fill item per thread (replaces fill kernel).
__global__ __launch_bounds__(512, 4) void edge_fused_kernel(
    const float* __restrict__ node, const float* __restrict__ edge,
    const int* __restrict__ edgeIdx,
    const int* __restrict__ e2n_r, const int* __restrict__ e2n_c,
    const float* __restrict__ e2n_v,
    u32* __restrict__ rcnt, int2* __restrict__ buck, int4* __restrict__ ovf,
    const float* __restrict__ lng, const float* __restrict__ lnb,
    const u16* __restrict__ w1r, const float* __restrict__ b1,
    const u16* __restrict__ w2r, const float* __restrict__ b2,
    __half* __restrict__ e_h, float* __restrict__ out_edge) {
  const int lane = threadIdx.x & 63, wid = threadIdx.x >> 6;   // 0..7
  const int l15 = lane & 15, gq = lane >> 4;
  const int row0 = blockIdx.x * 64;

  __shared__ __align__(16) u16 xp[64 * 384];      // 48 KB: x, then h (in place)
  __shared__ __align__(16) float er[64 * 128];    // 32 KB: edge residual cache

  // ---- fused COO->row-bucket fill (1 item/thread; first ~977 blocks) ----
  {
    int k = blockIdx.x * 512 + (int)threadIdx.x;
    if (k < NNZV) {
      int r = e2n_r[k];
      u32 p = atomicAdd(&rcnt[r], 1u);
      if (p < RCAP) {
        buck[(size_t)r * RCAP + p] = make_int2(e2n_c[k], __float_as_int(e2n_v[k]));
      } else {
        u32 q = atomicAdd(&rcnt[N_NODE], 1u);
        if (q < OVFCAP) ovf[q] = make_int4(r, e2n_c[k], __float_as_int(e2n_v[k]), 0);
      }
    }
  }

  const bf16x8* w1v = (const bf16x8*)w1r + (size_t)wid * (12 * 192) + lane;
  bf16x8 br[3][3];
#define LDB1(s, b) { br[b][0] = w1v[(s) * 192]; br[b][1] = w1v[(s) * 192 + 64]; \
                     br[b][2] = w1v[(s) * 192 + 128]; }
  LDB1(0, 0); LDB1(1, 1); LDB1(2, 2);

  float ga[6], be[6];
#pragma unroll
  for (int s = 0; s < 3; ++s) {
    float2 g2 = *(const float2*)&lng[s * 128 + 2 * lane];
    float2 b2v = *(const float2*)&lnb[s * 128 + 2 * lane];
    ga[2 * s] = g2.x; ga[2 * s + 1] = g2.y;
    be[2 * s] = b2v.x; be[2 * s + 1] = b2v.y;
  }
  {
    u32 oe[8], oa[8], ob[8];
#pragma unroll
    for (int t = 0; t < 8; ++t) {
      int g = row0 + wid * 8 + t; if (g > N_EDGE - 1) g = N_EDGE - 1;
      int2 ab = ldo<int2>(edgeIdx, (u32)g * 8);
      oe[t] = (u32)g * 512 + lane * 8;
      oa[t] = (u32)ab.x * 512 + lane * 8;
      ob[t] = (u32)ab.y * 512 + lane * 8;
    }
    float2 v0[8], v1[8], v2[8];
#pragma unroll
    for (int t = 0; t < 8; ++t) {
      v0[t] = ldo<float2>(edge, oe[t]);
      v1[t] = ldo<float2>(node, oa[t]);
      v2[t] = ldo<float2>(node, ob[t]);
    }
#pragma unroll
    for (int t = 0; t < 8; ++t) {
      int lr = wid * 8 + t;
      *(float2*)&er[lr * 128 + 2 * lane] = v0[t];
      float s  = v0[t].x + v0[t].y + v1[t].x + v1[t].y + v2[t].x + v2[t].y;
      float ss = v0[t].x*v0[t].x + v0[t].y*v0[t].y + v1[t].x*v1[t].x +
                 v1[t].y*v1[t].y + v2[t].x*v2[t].x + v2[t].y*v2[t].y;
#pragma unroll
      for (int m = 1; m < 64; m <<= 1) { s += __shfl_xor(s, m); ss += __shfl_xor(ss, m); }
      float mean = s * (1.0f / 384.0f);
      float var  = ss * (1.0f / 384.0f) - mean * mean;
      float rstd = rsqrtf(var + 1e-5f);
      float2 vv[3] = {v0[t], v1[t], v2[t]};
#pragma unroll
      for (int sg = 0; sg < 3; ++sg) {
        float y0 = (vv[sg].x - mean) * rstd * ga[2 * sg]     + be[2 * sg];
        float y1 = (vv[sg].y - mean) * rstd * ga[2 * sg + 1] + be[2 * sg + 1];
        int sl = (sg * 16 + (lane >> 2)) ^ (lr & 15);
        *(u32*)&xp[lr * 384 + sl * 8 + (lane & 3) * 2] = pk_bf16(y0, y1);
      }
    }
  }
  WAITLGKM0(); SCHEDB(); SBAR(); SCHEDB();

  f32x4 acc1[4][3];
#pragma unroll
  for (int nt = 0; nt < 3; ++nt) {
    float bv = b1[wid * 48 + nt * 16 + l15];
#pragma unroll
    for (int m = 0; m < 4; ++m) acc1[m][nt] = (f32x4){bv, bv, bv, bv};
  }
  int aoff[4];
#pragma unroll
  for (int m = 0; m < 4; ++m) aoff[m] = (m * 16 + l15) * 384;

#pragma unroll
  for (int s = 0; s < 12; ++s) {
    const int axi = ((s * 4 + gq) ^ l15) * 8;
    bf16x8 a[4];
#pragma unroll
    for (int m = 0; m < 4; ++m) a[m] = *(const bf16x8*)&xp[aoff[m] + axi];
    __builtin_amdgcn_s_setprio(1);
#pragma unroll
    for (int m = 0; m < 4; ++m)
#pragma unroll
      for (int nt = 0; nt < 3; ++nt)
        acc1[m][nt] = __builtin_amdgcn_mfma_f32_16x16x32_bf16(a[m], br[s % 3][nt], acc1[m][nt], 0, 0, 0);
    __builtin_amdgcn_s_setprio(0);
    if (s + 3 < 12) { LDB1(s + 3, s % 3); }
  }
  SCHEDB(); SBAR(); SCHEDB();

  const bf16x8* w2v = (const bf16x8*)w2r + (size_t)wid * (12 * 64) + lane;
  bf16x8 br2[3];
#define LDB2(s, b) { br2[b] = w2v[(s) * 64]; }
  LDB2(0, 0); LDB2(1, 1); LDB2(2, 2);
#pragma unroll
  for (int m = 0; m < 4; ++m)
#pragma unroll
    for (int nt = 0; nt < 3; ++nt) {
      const int c = wid * 48 + nt * 16 + l15;
#pragma unroll
      for (int j = 0; j < 4; ++j) {
        int r = m * 16 + gq * 4 + j;
        xp[r * 384 + (((c >> 3) ^ (r & 15)) * 8) + (c & 7)] = f2bf_fast(gelu_f(acc1[m][nt][j]));
      }
    }
  WAITLGKM0(); SCHEDB(); SBAR(); SCHEDB();

  float b2v = b2[wid * 16 + l15];
  f32x4 acc2[4];
#pragma unroll
  for (int m = 0; m < 4; ++m) acc2[m] = (f32x4){b2v, b2v, b2v, b2v};

#pragma unroll
  for (int g = 0; g < 12; ++g) {
    const int axi = ((g * 4 + gq) ^ l15) * 8;
    bf16x8 a[4];
#pragma unroll
    for (int m = 0; m < 4; ++m) a[m] = *(const bf16x8*)&xp[aoff[m] + axi];
    __builtin_amdgcn_s_setprio(1);
#pragma unroll
    for (int m = 0; m < 4; ++m)
      acc2[m] = __builtin_amdgcn_mfma_f32_16x16x32_bf16(a[m], br2[g % 3], acc2[m], 0, 0, 0);
    __builtin_amdgcn_s_setprio(0);
    if (g + 3 < 12) { LDB2(g + 3, g % 3); }
  }

  const int col = wid * 16 + l15;
#pragma unroll
  for (int m = 0; m < 4; ++m)
#pragma unroll
    for (int j = 0; j < 4; ++j) {
      int lr = m * 16 + gq * 4 + j;
      int r = row0 + lr;
      if (r < N_EDGE) {
        __half hv = __float2half(acc2[m][j]);
        sto<__half>(e_h, (u32)r * 256 + col * 2, hv);
        sto<float>(out_edge, (u32)r * 512 + col * 4, er[lr * 128 + col] + __half2float(hv));
      }
    }
#undef LDB1
#undef LDB2
}

// ==================== fused node MLP (r17-proven) ============================
__global__ __launch_bounds__(512, 4) void node_fused_kernel(
    const float* __restrict__ node, const __half* __restrict__ agg,
    const float* __restrict__ lng, const float* __restrict__ lnb,
    const u16* __restrict__ w1r, const float* __restrict__ b1,
    const u16* __restrict__ w2r, const float* __restrict__ b2,
    float* __restrict__ out_node) {
  const int lane = threadIdx.x & 63, wid = threadIdx.x >> 6;
  const int l15 = lane & 15, gq = lane >> 4;
  const int row0 = blockIdx.x * 64;

  __shared__ __align__(16) u16 xp[64 * 256];      // 32 KB: x, then h
  __shared__ __align__(16) float nr[64 * 128];    // 32 KB: node residual cache

  const bf16x8* w1v = (const bf16x8*)w1r + (size_t)wid * (8 * 128) + lane;
  bf16x8 br[3][2];
#define NLDB1(s, b) { br[b][0] = w1v[(s) * 128]; br[b][1] = w1v[(s) * 128 + 64]; }
  NLDB1(0, 0); NLDB1(1, 1); NLDB1(2, 2);

  float ga[4], be[4];
#pragma unroll
  for (int s = 0; s < 2; ++s) {
    float2 g2 = *(const float2*)&lng[s * 128 + 2 * lane];
    float2 b2v = *(const float2*)&lnb[s * 128 + 2 * lane];
    ga[2 * s] = g2.x; ga[2 * s + 1] = g2.y;
    be[2 * s] = b2v.x; be[2 * s + 1] = b2v.y;
  }
  {
    float2 v0[8], v1[8];
#pragma unroll
    for (int t = 0; t < 8; ++t) {
      int g = row0 + wid * 8 + t; if (g > N_NODE - 1) g = N_NODE - 1;
      v0[t] = ldo<float2>(node, (u32)g * 512 + lane * 8);
      v1[t] = __half22float2(ldo<__half2>(agg, (u32)g * 256 + lane * 4));
    }
#pragma unroll
    for (int t = 0; t < 8; ++t) {
      int lr = wid * 8 + t;
      *(float2*)&nr[lr * 128 + 2 * lane] = v0[t];
      float s  = v0[t].x + v0[t].y + v1[t].x + v1[t].y;
      float ss = v0[t].x*v0[t].x + v0[t].y*v0[t].y + v1[t].x*v1[t].x + v1[t].y*v1[t].y;
#pragma unroll
      for (int m = 1; m < 64; m <<= 1) { s += __shfl_xor(s, m); ss += __shfl_xor(ss, m); }
      float mean = s * (1.0f / 256.0f);
      float var  = ss * (1.0f / 256.0f) - mean * mean;
      float rstd = rsqrtf(var + 1e-5f);
      float2 vv[2] = {v0[t], v1[t]};
#pragma unroll
      for (int sg = 0; sg < 2; ++sg) {
        float y0 = (vv[sg].x - mean) * rstd * ga[2 * sg]     + be[2 * sg];
        float y1 = (vv[sg].y - mean) * rstd * ga[2 * sg + 1] + be[2 * sg + 1];
        int sl = (sg * 16 + (lane >> 2)) ^ (lr & 15);
        *(u32*)&xp[lr * 256 + sl * 8 + (lane & 3) * 2] = pk_bf16(y0, y1);
      }
    }
  }
  WAITLGKM0(); SCHEDB(); SBAR(); SCHEDB();

  f32x4 acc1[4][2];
#pragma unroll
  for (int nt = 0; nt < 2; ++nt) {
    float bv = b1[wid * 32 + nt * 16 + l15];
#pragma unroll
    for (int m = 0; m < 4; ++m) acc1[m][nt] = (f32x4){bv, bv, bv, bv};
  }
  int aoff[4];
#pragma unroll
  for (int m = 0; m < 4; ++m) aoff[m] = (m * 16 + l15) * 256;

#pragma unroll
  for (int s = 0; s < 8; ++s) {
    const int axi = ((s * 4 + gq) ^ l15) * 8;
    bf16x8 a[4];
#pragma unroll
    for (int m = 0; m < 4; ++m) a[m] = *(const bf16x8*)&xp[aoff[m] + axi];
    __builtin_amdgcn_s_setprio(1);
#pragma unroll
    for (int m = 0; m < 4; ++m)
#pragma unroll
      for (int nt = 0; nt < 2; ++nt)
        acc1[m][nt] = __builtin_amdgcn_mfma_f32_16x16x32_bf16(a[m], br[s % 3][nt], acc1[m][nt], 0, 0, 0);
    __builtin_amdgcn_s_setprio(0);
    if (s + 3 < 8) { NLDB1(s + 3, s % 3); }
  }
  SCHEDB(); SBAR(); SCHEDB();

  const bf16x8* w2v = (const bf16x8*)w2r + (size_t)wid * (8 * 64) + lane;
  bf16x8 br2[3];
#define NLDB2(s, b) { br2[b] = w2v[(s) * 64]; }
  NLDB2(0, 0); NLDB2(1, 1); NLDB2(2, 2);
#pragma unroll
  for (int m = 0; m < 4; ++m)
#pragma unroll
    for (int nt = 0; nt < 2; ++nt) {
      const int c = wid * 32 + nt * 16 + l15;
#pragma unroll
      for (int j = 0; j < 4; ++j) {
        int r = m * 16 + gq * 4 + j;
        xp[r * 256 + (((c >> 3) ^ (r & 15)) * 8) + (c & 7)] = f2bf_fast(gelu_f(acc1[m][nt][j]));
      }
    }
  WAITLGKM0(); SCHEDB(); SBAR(); SCHEDB();

  float b2v = b2[wid * 16 + l15];
  f32x4 acc2[4];
#pragma unroll
  for (int m = 0; m < 4; ++m) acc2[m] = (f32x4){b2v, b2v, b2v, b2v};

#pragma unroll
  for (int g = 0; g < 8; ++g) {
    const int axi = ((g * 4 + gq) ^ l15) * 8;
    bf16x8 a[4];
#pragma unroll
    for (int m = 0; m < 4; ++m) a[m] = *(const bf16x8*)&xp[aoff[m] + axi];
    __builtin_amdgcn_s_setprio(1);
#pragma unroll
    for (int m = 0; m < 4; ++m)
      acc2[m] = __builtin_amdgcn_mfma_f32_16x16x32_bf16(a[m], br2[g % 3], acc2[m], 0, 0, 0);
    __builtin_amdgcn_s_setprio(0);
    if (g + 3 < 8) { NLDB2(g + 3, g % 3); }
  }

  const int col = wid * 16 + l15;
#pragma unroll
  for (int m = 0; m < 4; ++m)
#pragma unroll
    for (int j = 0; j < 4; ++j) {
      int lr = m * 16 + gq * 4 + j;
      int r = row0 + lr;
      if (r < N_NODE) {
        sto<float>(out_node, (u32)r * 512 + col * 4, nr[lr * 128 + col] + acc2[m][j]);
      }
    }
#undef NLDB1
#undef NLDB2
}

extern "C" void kernel_launch(void* const* d_in, const int* in_sizes, int n_in,
                              void* d_out, int out_size, void* d_ws, size_t ws_size,
                              hipStream_t stream) {
  (void)in_sizes; (void)n_in; (void)out_size; (void)ws_size;
  const float* node    = (const float*)d_in[0];
  const float* edge    = (const float*)d_in[1];
  const int*   edgeIdx = (const int*)d_in[2];
  const int*   e2n_r   = (const int*)d_in[3];
  const int*   e2n_c   = (const int*)d_in[4];
  const float* e2n_v   = (const float*)d_in[5];
  const float* n1g     = (const float*)d_in[6];
  const float* n1b     = (const float*)d_in[7];
  const float* n2g     = (const float*)d_in[8];
  const float* n2b     = (const float*)d_in[9];
  const float* ew1     = (const float*)d_in[10];
  const float* eb1     = (const float*)d_in[11];
  const float* ew2     = (const float*)d_in[12];
  const float* eb2     = (const float*)d_in[13];
  const float* nw1     = (const float*)d_in[14];
  const float* nb1     = (const float*)d_in[15];
  const float* nw2     = (const float*)d_in[16];
  const float* nb2     = (const float*)d_in[17];

  float* out_node = (float*)d_out;
  float* out_edge = out_node + (size_t)N_NODE * 128;

  char* w = (char*)d_ws;
  auto alloc = [&](size_t bytes) { char* p = w; w += (bytes + 255) & ~(size_t)255; return p; };
  u16* ew1r = (u16*)alloc((size_t)384 * 384 * 2);
  u16* ew2r = (u16*)alloc((size_t)384 * 128 * 2);
  u16* nw1r = (u16*)alloc((size_t)256 * 256 * 2);
  u16* nw2r = (u16*)alloc((size_t)256 * 128 * 2);
  __half* agg = (__half*)alloc((size_t)N_NODE * 128 * 2);
  __half* e_h = (__half*)alloc((size_t)N_EDGE * 128 * 2);
  u32* rcnt = (u32*)alloc((size_t)(N_NODE + 1) * 4);
  int4* ovf = (int4*)alloc((size_t)OVFCAP * 16);
  int2* buck = (int2*)alloc(((size_t)N_NODE * RCAP + 64) * 8);  // +slack for unroll-4 reads

  prep_kernel<<<1024, 256, 0, stream>>>(ew1, ew2, nw1, nw2,
                                        ew1r, ew2r, nw1r, nw2r, rcnt);

  edge_fused_kernel<<<(N_EDGE + 63) / 64, 512, 0, stream>>>(
      node, edge, edgeIdx, e2n_r, e2n_c, e2n_v, rcnt, buck, ovf,
      n1g, n1b, ew1r, eb1, ew2r, eb2, e_h, out_edge);

  agg_gather_kernel<<<(N_NODE + 3) / 4, 256, 0, stream>>>(rcnt, buck, e_h, agg);

  ovf_scatter_kernel<<<16, 256, 0, stream>>>(ovf, rcnt, e_h, agg);

  node_fused_kernel<<<(N_NODE + 63) / 64, 512, 0, stream>>>(
      node, agg, n2g, n2b, nw1r, nb1, nw2r, nb2, out_node);
}